// Round 1
// baseline (469.710 us; speedup 1.0000x reference)
//
#include <hip/hip_runtime.h>
#include <hip/hip_bf16.h>
#include <stdint.h>

// EdgeModel: out = relu(concat(ek, vrk, vsk, u[batch]) @ W1 + b1) @ W2 + b2
// E=320000, IN_CH=384, HID=128, TGT=64.
//
// Barrier-free streaming design: each wave owns 32 edges x all 128 hid.
//  - x fragments loaded directly from global f32 (no LDS staging, no syncthreads),
//    cvt to bf16 in-register, fed to MFMA. Steady HBM demand, no vmcnt(0) drains.
//  - W1/W2 pre-packed into exact MFMA A-fragment order -> each A-load is
//    base + lane*16 + imm, 1KB/instruction, L2-resident.
//  - h bounced through a private 8KB LDS slice per wave (lgkmcnt only).
//  - out bounced through the same slice as f32 -> 1KB contiguous store
//    instructions (fixes 1.83x write amplification).

typedef __bf16 bf16;
typedef __attribute__((ext_vector_type(8))) __bf16 bf16x8;
typedef __attribute__((ext_vector_type(4))) __bf16 bf16x4;
typedef __attribute__((ext_vector_type(4))) float floatx4;

__device__ __forceinline__ bf16x8 cvt_b8(floatx4 a, floatx4 b) {
  bf16x8 r;
  r[0] = (bf16)a.x; r[1] = (bf16)a.y; r[2] = (bf16)a.z; r[3] = (bf16)a.w;
  r[4] = (bf16)b.x; r[5] = (bf16)b.y; r[6] = (bf16)b.z; r[7] = (bf16)b.w;
  return r;
}
__device__ __forceinline__ bf16x4 cvt_b4(floatx4 v) {
  bf16x4 r;
  r[0] = (bf16)v.x; r[1] = (bf16)v.y; r[2] = (bf16)v.z; r[3] = (bf16)v.w;
  return r;
}

// ---- pre-kernel: pack W1 [384][128] f32 and W2 [128][64] f32 into bf16
// MFMA A-fragment order. Fragment id b, lane l, j=0..7:
//   w1p[(b*64+l)*8+j] = W1[kc*32 + (l>>4)*8 + j][hf*16 + (l&15)],  b = kc*8+hf
//   w2p[(b*64+l)*8+j] = W2[ks*32 + (l>>4)*8 + j][tf*16 + (l&15)],  b = ks*4+tf
__global__ void pack_pre(const float* __restrict__ W1, bf16* __restrict__ w1p,
                         const float* __restrict__ W2, bf16* __restrict__ w2p) {
  int b = blockIdx.x, lane = threadIdx.x;
  int mm = lane & 15, qq = lane >> 4;
  if (b < 96) {
    int kc = b >> 3, hf = b & 7;
    bf16x8 r;
    #pragma unroll
    for (int j = 0; j < 8; ++j)
      r[j] = (bf16)W1[(kc * 32 + qq * 8 + j) * 128 + hf * 16 + mm];
    *(bf16x8*)(w1p + ((long)b * 64 + lane) * 8) = r;
  } else {
    int bb = b - 96;
    int ks = bb >> 2, tf = bb & 3;
    bf16x8 r;
    #pragma unroll
    for (int j = 0; j < 8; ++j)
      r[j] = (bf16)W2[(ks * 32 + qq * 8 + j) * 64 + tf * 16 + mm];
    *(bf16x8*)(w2p + ((long)bb * 64 + lane) * 8) = r;
  }
}

// 32 KB LDS (4 waves x 8KB private slices); VGPR cap 128 -> 4 blocks/CU.
__global__ __launch_bounds__(256, 4) void edge_mlp(
    const float* __restrict__ ek, const float* __restrict__ vrk, const float* __restrict__ vsk,
    const float* __restrict__ u, const int* __restrict__ batch,
    const bf16* __restrict__ w1p, const float* __restrict__ b1,
    const bf16* __restrict__ w2p, const float* __restrict__ b2,
    float* __restrict__ out)
{
  __shared__ __align__(16) bf16 smem[16384];  // 32 KB
  const int tid  = threadIdx.x;
  const int lane = tid & 63;
  const int wv   = tid >> 6;
  const int m    = lane & 15;
  const int q    = lane >> 4;
  bf16* hs = smem + wv * 4096;          // this wave's [32 edge][128 hid] slice

  const int e0 = blockIdx.x * 128 + wv * 32;   // wave's 32 edges

  // per-lane row pointers (q*8 f32 k-offset folded in)
  const float* px[4][2];                // [src: ek,vrk,vsk,u][ef]
  #pragma unroll
  for (int ef = 0; ef < 2; ++ef) {
    int e = e0 + ef * 16 + m;
    px[0][ef] = ek  + (long)e * 64  + q * 8;
    px[1][ef] = vrk + (long)e * 128 + q * 8;
    px[2][ef] = vsk + (long)e * 128 + q * 8;
    px[3][ef] = u   + (long)batch[e] * 64 + q * 8;
  }
  const bf16* wp = w1p + lane * 8;

  // ---- GEMM1: acc[hf][ef], D[hid][edge]; K = 384 in 12 steps of 32
  floatx4 acc[8][2] = {};
  #pragma unroll
  for (int kc = 0; kc < 12; ++kc) {
    const int src = (kc < 2) ? 0 : (kc < 6) ? 1 : (kc < 10) ? 2 : 3;
    const int off = (kc < 2) ? kc * 32
                  : (kc < 6) ? (kc - 2) * 32
                  : (kc < 10) ? (kc - 6) * 32 : (kc - 10) * 32;
    bf16x8 xb[2];
    #pragma unroll
    for (int ef = 0; ef < 2; ++ef) {
      floatx4 v0 = *(const floatx4*)(px[src][ef] + off);
      floatx4 v1 = *(const floatx4*)(px[src][ef] + off + 4);
      xb[ef] = cvt_b8(v0, v1);
    }
    #pragma unroll
    for (int hf = 0; hf < 8; ++hf) {
      bf16x8 af = *(const bf16x8*)(wp + (kc * 8 + hf) * 512);
      acc[hf][0] = __builtin_amdgcn_mfma_f32_16x16x32_bf16(af, xb[0], acc[hf][0], 0, 0, 0);
      acc[hf][1] = __builtin_amdgcn_mfma_f32_16x16x32_bf16(af, xb[1], acc[hf][1], 0, 0, 0);
    }
  }

  // ---- epilogue 1: bias + relu + bf16 -> wave-private LDS h (XOR-16 swizzle)
  #pragma unroll
  for (int hf = 0; hf < 8; ++hf) {
    floatx4 b1v = *(const floatx4*)(b1 + hf * 16 + q * 4);
    #pragma unroll
    for (int ef = 0; ef < 2; ++ef) {
      floatx4 v = acc[hf][ef] + b1v;
      v.x = v.x > 0.f ? v.x : 0.f;
      v.y = v.y > 0.f ? v.y : 0.f;
      v.z = v.z > 0.f ? v.z : 0.f;
      v.w = v.w > 0.f ? v.w : 0.f;
      int r_e  = ef * 16 + m;
      int c    = hf * 2 + (q >> 1);          // 16B chunk of hid0 = hf*16+q*4
      int phys = c ^ (r_e & 15);
      *(bf16x4*)(hs + r_e * 128 + phys * 8 + (q & 1) * 4) = cvt_b4(v);
    }
  }
  asm volatile("s_waitcnt lgkmcnt(0)" ::: "memory");   // within-wave write->read order
  __builtin_amdgcn_sched_barrier(0);

  // ---- GEMM2: acc2[tf][ef], D[tgt][edge]; K = 128 in 4 steps of 32
  floatx4 acc2[4][2] = {};
  const bf16* wq = w2p + lane * 8;
  #pragma unroll
  for (int ks = 0; ks < 4; ++ks) {
    bf16x8 hb[2];
    #pragma unroll
    for (int ef = 0; ef < 2; ++ef) {
      int r_e  = ef * 16 + m;
      int phys = (ks * 4 + q) ^ (r_e & 15);
      hb[ef] = *(const bf16x8*)(hs + r_e * 128 + phys * 8);
    }
    #pragma unroll
    for (int tf = 0; tf < 4; ++tf) {
      bf16x8 a2 = *(const bf16x8*)(wq + (ks * 4 + tf) * 512);
      acc2[tf][0] = __builtin_amdgcn_mfma_f32_16x16x32_bf16(a2, hb[0], acc2[tf][0], 0, 0, 0);
      acc2[tf][1] = __builtin_amdgcn_mfma_f32_16x16x32_bf16(a2, hb[1], acc2[tf][1], 0, 0, 0);
    }
  }

  // ---- epilogue 2: bias, bounce f32 through LDS slice, store full lines
  asm volatile("s_waitcnt lgkmcnt(0)" ::: "memory");   // h reads done before overwrite
  __builtin_amdgcn_sched_barrier(0);
  float* fs = (float*)hs;                              // alias as [32 edge][64 tgt] f32
  #pragma unroll
  for (int tf = 0; tf < 4; ++tf) {
    floatx4 b2v = *(const floatx4*)(b2 + tf * 16 + q * 4);
    #pragma unroll
    for (int ef = 0; ef < 2; ++ef) {
      floatx4 v = acc2[tf][ef] + b2v;
      int r_e  = ef * 16 + m;
      int c    = tf * 4 + q;                 // 16B chunk of tgt0 = tf*16+q*4
      int phys = c ^ (r_e & 15);
      *(floatx4*)(fs + r_e * 64 + phys * 4) = v;
    }
  }
  asm volatile("s_waitcnt lgkmcnt(0)" ::: "memory");
  __builtin_amdgcn_sched_barrier(0);

  float* outp = out + (long)e0 * 64;        // wave's 8KB contiguous out region
  #pragma unroll
  for (int i = 0; i < 8; ++i) {
    int r_e  = i * 4 + q;
    int phys = m ^ (r_e & 15);
    floatx4 v = *(const floatx4*)(fs + r_e * 64 + phys * 4);
    *(floatx4*)(outp + i * 256 + lane * 4) = v;   // 1KB contiguous per instruction
  }
}

extern "C" void kernel_launch(void* const* d_in, const int* in_sizes, int n_in,
                              void* d_out, int out_size, void* d_ws, size_t ws_size,
                              hipStream_t stream) {
  const float* ek    = (const float*)d_in[0];
  const float* vrk   = (const float*)d_in[1];
  const float* vsk   = (const float*)d_in[2];
  const float* u     = (const float*)d_in[3];
  const int*   batch = (const int*)d_in[4];
  const float* W1    = (const float*)d_in[5];
  const float* b1    = (const float*)d_in[6];
  const float* W2    = (const float*)d_in[7];
  const float* b2    = (const float*)d_in[8];
  float* out = (float*)d_out;

  bf16* w1p = (bf16*)d_ws;               // 96 frags * 64 lanes * 8 = 96 KB
  bf16* w2p = (bf16*)d_ws + 49152;       // 16 frags * 64 lanes * 8 = 16 KB

  pack_pre<<<112, 64, 0, stream>>>(W1, w1p, W2, w2p);
  edge_mlp<<<2500, 256, 0, stream>>>(ek, vrk, vsk, u, batch, w1p, b1, w2p, b2, out);
}

// Round 2
// 424.975 us; speedup vs baseline: 1.1053x; 1.1053x over previous
//
#include <hip/hip_runtime.h>
#include <hip/hip_bf16.h>
#include <stdint.h>

// EdgeModel: out = relu(concat(ek, vrk, vsk, u[batch]) @ W1 + b1) @ W2 + b2
// E=320000, IN_CH=384, HID=128, TGT=64.
//
// Round-2 design: per-wave LDS-DMA pipeline, zero block barriers.
//  - Each wave owns 32 edges. x staged in f32 via global_load_lds (no dest
//    VGPRs -> deep in-flight queue) into a wave-private double-buffered 4KB
//    LDS chunk; counted s_waitcnt vmcnt(12) per step (never drains to 0).
//  - XOR-16B swizzle applied on the GLOBAL source side (linear LDS dest),
//    read back with the same involution -> ~2-way-max bank conflicts.
//  - W1/W2 pre-packed in MFMA A-fragment order (L2-resident, 1KB/load).
//  - h bounced through the same wave-private slice (lgkmcnt only);
//    out bounced as f32 -> 1KB contiguous store instructions.

typedef __bf16 bf16;
typedef __attribute__((ext_vector_type(8))) __bf16 bf16x8;
typedef __attribute__((ext_vector_type(4))) __bf16 bf16x4;
typedef __attribute__((ext_vector_type(4))) float floatx4;

__device__ __forceinline__ void ldg2lds16(const void* g, void* l) {
  __builtin_amdgcn_global_load_lds((__attribute__((address_space(1))) void*)g,
                                   (__attribute__((address_space(3))) void*)l,
                                   16, 0, 0);
}

__device__ __forceinline__ bf16x8 cvt_b8(floatx4 a, floatx4 b) {
  bf16x8 r;
  r[0] = (bf16)a.x; r[1] = (bf16)a.y; r[2] = (bf16)a.z; r[3] = (bf16)a.w;
  r[4] = (bf16)b.x; r[5] = (bf16)b.y; r[6] = (bf16)b.z; r[7] = (bf16)b.w;
  return r;
}
__device__ __forceinline__ bf16x4 cvt_b4(floatx4 v) {
  bf16x4 r;
  r[0] = (bf16)v.x; r[1] = (bf16)v.y; r[2] = (bf16)v.z; r[3] = (bf16)v.w;
  return r;
}

// ---- pre-kernel: pack W1 [384][128] f32 and W2 [128][64] f32 into bf16
// MFMA A-fragment order. Fragment id b, lane l, j=0..7:
//   w1p[(b*64+l)*8+j] = W1[kc*32 + (l>>4)*8 + j][hf*16 + (l&15)],  b = kc*8+hf
//   w2p[(b*64+l)*8+j] = W2[ks*32 + (l>>4)*8 + j][tf*16 + (l&15)],  b = ks*4+tf
__global__ void pack_pre(const float* __restrict__ W1, bf16* __restrict__ w1p,
                         const float* __restrict__ W2, bf16* __restrict__ w2p) {
  int b = blockIdx.x, lane = threadIdx.x;
  int mm = lane & 15, qq = lane >> 4;
  if (b < 96) {
    int kc = b >> 3, hf = b & 7;
    bf16x8 r;
    #pragma unroll
    for (int j = 0; j < 8; ++j)
      r[j] = (bf16)W1[(kc * 32 + qq * 8 + j) * 128 + hf * 16 + mm];
    *(bf16x8*)(w1p + ((long)b * 64 + lane) * 8) = r;
  } else {
    int bb = b - 96;
    int ks = bb >> 2, tf = bb & 3;
    bf16x8 r;
    #pragma unroll
    for (int j = 0; j < 8; ++j)
      r[j] = (bf16)W2[(ks * 32 + qq * 8 + j) * 64 + tf * 16 + mm];
    *(bf16x8*)(w2p + ((long)bb * 64 + lane) * 8) = r;
  }
}

// 32 KB LDS (4 waves x 8KB private slices). (256,3): 170 unified regs/wave,
// enough for ~100 VGPR + 64 AGPR acc with NO spills (spills would break the
// manual vmcnt counting).
__global__ __launch_bounds__(256, 3) void edge_mlp(
    const float* __restrict__ ek, const float* __restrict__ vrk, const float* __restrict__ vsk,
    const float* __restrict__ u, const int* __restrict__ batch,
    const bf16* __restrict__ w1p, const float* __restrict__ b1,
    const bf16* __restrict__ w2p, const float* __restrict__ b2,
    float* __restrict__ out)
{
  __shared__ __align__(16) char smem[32768];  // 4 waves x 8 KB
  const int tid  = threadIdx.x;
  const int lane = tid & 63;
  const int wv   = tid >> 6;
  const int m    = lane & 15;
  const int q    = lane >> 4;
  char* wsl = smem + wv * 8192;        // wave slice: x dbuf (2x4KB); later h

  const int e0 = blockIdx.x * 128 + wv * 32;   // wave's 32 edges
  const int rl = lane >> 3;                    // 0..7: row within 8-row group
  const int cswz = ((lane & 7) ^ rl) * 16;     // source-side XOR swizzle (bytes)

  // u gather row indices for the DMA (batch is sorted; L2-resident)
  int ubr[4];
  #pragma unroll
  for (int i = 0; i < 4; ++i) ubr[i] = batch[e0 + i * 8 + rl];

  const char* cek = (const char*)ek  + (long)e0 * 256;
  const char* cvr = (const char*)vrk + (long)e0 * 512;
  const char* cvs = (const char*)vsk + (long)e0 * 512;
  const char* cu_ = (const char*)u;

  // stage k-chunk kc (32 edges x 32 k, f32) into wave slice at byte bufoff.
  // LDS dest is the wave-uniform base (HW adds lane*16); global src carries
  // the per-lane inverse swizzle.
  auto stage = [&](int kc, int bufoff) {
    #pragma unroll
    for (int i = 0; i < 4; ++i) {
      int r = i * 8 + rl;
      const char* src;
      if (kc < 2)       src = cek + (long)r * 256 + kc * 128 + cswz;
      else if (kc < 6)  src = cvr + (long)r * 512 + (kc - 2) * 128 + cswz;
      else if (kc < 10) src = cvs + (long)r * 512 + (kc - 6) * 128 + cswz;
      else              src = cu_ + (long)ubr[i] * 256 + (kc - 10) * 128 + cswz;
      ldg2lds16(src, wsl + bufoff + i * 1024);
    }
  };

  const bf16* wp = w1p + lane * 8;
  const int off0 = ((q << 1) ^ (m & 7)) * 16;  // ds_read swizzled chunk offset

  // ---- GEMM1: acc[hf][ef] = D[hid][edge]; K = 384 in 12 chunks of 32
  stage(0, 0);
  floatx4 acc[8][2] = {};
  #pragma unroll
  for (int kc = 0; kc < 12; ++kc) {
    const int curoff = (kc & 1) * 4096;
    // W fragments for this chunk (L2-resident; in flight across the vmcnt)
    bf16x8 wr[8];
    #pragma unroll
    for (int hf = 0; hf < 8; ++hf)
      wr[hf] = *(const bf16x8*)(wp + (kc * 8 + hf) * 512);
    // queue next x chunk
    if (kc < 11) stage(kc + 1, curoff ^ 4096);
    __builtin_amdgcn_sched_barrier(0);
    // counted wait: chunk kc landed; W(kc) [8] + DMA(kc+1) [4] stay in flight
    if (kc < 11) asm volatile("s_waitcnt vmcnt(12)" ::: "memory");
    else         asm volatile("s_waitcnt vmcnt(8)"  ::: "memory");
    __builtin_amdgcn_sched_barrier(0);
    // x fragments: ds_read f32 -> cvt bf16
    bf16x8 xv[2];
    #pragma unroll
    for (int ef = 0; ef < 2; ++ef) {
      const char* p = wsl + curoff + (ef * 16 + m) * 128;
      floatx4 lo = *(const floatx4*)(p + off0);
      floatx4 hi = *(const floatx4*)(p + (off0 ^ 16));
      xv[ef] = cvt_b8(lo, hi);
    }
    #pragma unroll
    for (int hf = 0; hf < 8; ++hf) {
      acc[hf][0] = __builtin_amdgcn_mfma_f32_16x16x32_bf16(wr[hf], xv[0], acc[hf][0], 0, 0, 0);
      acc[hf][1] = __builtin_amdgcn_mfma_f32_16x16x32_bf16(wr[hf], xv[1], acc[hf][1], 0, 0, 0);
    }
  }

  // ---- epilogue 1: bias + relu + bf16 -> wave-private LDS h (XOR-16 swizzle)
  // (aliases the x dbuf; safe: all x ds_reads are consumed by GEMM1's MFMAs)
  bf16* hsp = (bf16*)wsl;                    // [32 edge][128 hid]
  #pragma unroll
  for (int hf = 0; hf < 8; ++hf) {
    floatx4 b1v = *(const floatx4*)(b1 + hf * 16 + q * 4);
    #pragma unroll
    for (int ef = 0; ef < 2; ++ef) {
      floatx4 v = acc[hf][ef] + b1v;
      v.x = v.x > 0.f ? v.x : 0.f;
      v.y = v.y > 0.f ? v.y : 0.f;
      v.z = v.z > 0.f ? v.z : 0.f;
      v.w = v.w > 0.f ? v.w : 0.f;
      int r_e  = ef * 16 + m;
      int c    = hf * 2 + (q >> 1);          // 16B chunk of hid0 = hf*16+q*4
      int phys = c ^ (r_e & 15);
      *(bf16x4*)(hsp + r_e * 128 + phys * 8 + (q & 1) * 4) = cvt_b4(v);
    }
  }
  asm volatile("s_waitcnt lgkmcnt(0)" ::: "memory");   // h writes visible
  __builtin_amdgcn_sched_barrier(0);

  // ---- GEMM2: acc2[tf][ef] = D[tgt][edge]; K = 128 in 4 steps of 32
  floatx4 acc2[4][2] = {};
  const bf16* wq = w2p + lane * 8;
  bf16x8 w2r[16];
  #pragma unroll
  for (int f = 0; f < 16; ++f) w2r[f] = *(const bf16x8*)(wq + f * 512);
  #pragma unroll
  for (int ks = 0; ks < 4; ++ks) {
    bf16x8 hb[2];
    #pragma unroll
    for (int ef = 0; ef < 2; ++ef) {
      int r_e  = ef * 16 + m;
      int phys = (ks * 4 + q) ^ (r_e & 15);
      hb[ef] = *(const bf16x8*)(hsp + r_e * 128 + phys * 8);
    }
    #pragma unroll
    for (int tf = 0; tf < 4; ++tf) {
      acc2[tf][0] = __builtin_amdgcn_mfma_f32_16x16x32_bf16(w2r[ks * 4 + tf], hb[0], acc2[tf][0], 0, 0, 0);
      acc2[tf][1] = __builtin_amdgcn_mfma_f32_16x16x32_bf16(w2r[ks * 4 + tf], hb[1], acc2[tf][1], 0, 0, 0);
    }
  }

  // ---- epilogue 2: bias, bounce f32 through LDS slice, store full lines
  asm volatile("s_waitcnt lgkmcnt(0)" ::: "memory");   // h reads done before overwrite
  __builtin_amdgcn_sched_barrier(0);
  float* fs = (float*)wsl;                             // [32 edge][64 tgt] f32
  #pragma unroll
  for (int tf = 0; tf < 4; ++tf) {
    floatx4 b2v = *(const floatx4*)(b2 + tf * 16 + q * 4);
    #pragma unroll
    for (int ef = 0; ef < 2; ++ef) {
      floatx4 v = acc2[tf][ef] + b2v;
      int r_e  = ef * 16 + m;
      int c    = tf * 4 + q;                 // 16B chunk of tgt0 = tf*16+q*4
      int phys = c ^ (r_e & 15);
      *(floatx4*)(fs + r_e * 64 + phys * 4) = v;
    }
  }
  asm volatile("s_waitcnt lgkmcnt(0)" ::: "memory");
  __builtin_amdgcn_sched_barrier(0);

  float* outp = out + (long)e0 * 64;        // wave's 8KB contiguous out region
  #pragma unroll
  for (int i = 0; i < 8; ++i) {
    int r_e  = i * 4 + q;
    int phys = m ^ (r_e & 15);
    floatx4 v = *(const floatx4*)(fs + r_e * 64 + phys * 4);
    *(floatx4*)(outp + i * 256 + lane * 4) = v;   // 1KB contiguous per instruction
  }
}

extern "C" void kernel_launch(void* const* d_in, const int* in_sizes, int n_in,
                              void* d_out, int out_size, void* d_ws, size_t ws_size,
                              hipStream_t stream) {
  const float* ek    = (const float*)d_in[0];
  const float* vrk   = (const float*)d_in[1];
  const float* vsk   = (const float*)d_in[2];
  const float* u     = (const float*)d_in[3];
  const int*   batch = (const int*)d_in[4];
  const float* W1    = (const float*)d_in[5];
  const float* b1    = (const float*)d_in[6];
  const float* W2    = (const float*)d_in[7];
  const float* b2    = (const float*)d_in[8];
  float* out = (float*)d_out;

  bf16* w1p = (bf16*)d_ws;               // 96 frags * 64 lanes * 8 = 96 KB
  bf16* w2p = (bf16*)d_ws + 49152;       // 16 frags * 64 lanes * 8 = 16 KB

  pack_pre<<<112, 64, 0, stream>>>(W1, w1p, W2, w2p);
  edge_mlp<<<2500, 256, 0, stream>>>(ek, vrk, vsk, u, batch, w1p, b1, w2p, b2, out);
}

// Round 6
// 424.420 us; speedup vs baseline: 1.1067x; 1.0013x over previous
//
#include <hip/hip_runtime.h>
#include <hip/hip_bf16.h>
#include <stdint.h>

// EdgeModel: out = relu(concat(ek, vrk, vsk, u[batch]) @ W1 + b1) @ W2 + b2
// E=320000, IN_CH=384, HID=128, TGT=64.
//
// Round-6 = Round-5 resubmission. Rounds 3-5 failed at CONTAINER ACQUISITION
// (error JSON has no timing fields -> failure before kernel staging/compile;
// kernel never ran). Kernel re-audited: no barriers, no OOB, no spill risk,
// vmcnt queue simulation exact. Pre-committed rule: if this fails again the
// same way, Round 7 submits the byte-identical Round-2 kernel as an infra
// calibration probe.
//
// Design = Round-2 structure (passing, 156us) + W register double-buffer:
//  - Each wave owns 32 edges x all 128 hid; zero block barriers.
//  - x (f32) staged via global_load_lds into a wave-private 2x4KB double
//    buffer, prefetch distance 1; counted vmcnt(12) per step (vmcnt(0) only
//    on the final K-step).
//  - W fragments register-double-buffered (wcur/wnxt): W(kc+1) issued one
//    full iteration before use, BEFORE stage(kc+1) in program order.
//    Queue entering iter kc (oldest first): W(kc)8, stage(kc)4; body issues
//    W(kc+1)8, stage(kc+1)4; vmcnt(12) retires exactly W(kc)+stage(kc) and
//    keeps both prefetches in flight. VMEM retires in-order -> counts exact.
//  - XOR-16B swizzle on the GLOBAL source side (linear LDS dest), same
//    involution on ds_read.
//  - h bounced through the wave slice (lgkmcnt only); out bounced as f32 ->
//    1KB contiguous store instructions.
//  - __launch_bounds__(256,2): acc(64)+wcur(32)+wnxt(32)+addressing fits
//    with a huge margin -> NO scratch spills (spills are VMEM ops and would
//    corrupt the manual vmcnt counting).

typedef __bf16 bf16;
typedef __attribute__((ext_vector_type(8))) __bf16 bf16x8;
typedef __attribute__((ext_vector_type(4))) __bf16 bf16x4;
typedef __attribute__((ext_vector_type(4))) float floatx4;

__device__ __forceinline__ void ldg2lds16(const void* g, void* l) {
  __builtin_amdgcn_global_load_lds((__attribute__((address_space(1))) void*)g,
                                   (__attribute__((address_space(3))) void*)l,
                                   16, 0, 0);
}

__device__ __forceinline__ bf16x8 cvt_b8(floatx4 a, floatx4 b) {
  bf16x8 r;
  r[0] = (bf16)a.x; r[1] = (bf16)a.y; r[2] = (bf16)a.z; r[3] = (bf16)a.w;
  r[4] = (bf16)b.x; r[5] = (bf16)b.y; r[6] = (bf16)b.z; r[7] = (bf16)b.w;
  return r;
}
__device__ __forceinline__ bf16x4 cvt_b4(floatx4 v) {
  bf16x4 r;
  r[0] = (bf16)v.x; r[1] = (bf16)v.y; r[2] = (bf16)v.z; r[3] = (bf16)v.w;
  return r;
}

// ---- pre-kernel: pack W1 [384][128] f32 and W2 [128][64] f32 into bf16
// MFMA A-fragment order. Fragment id b, lane l, j=0..7:
//   w1p[(b*64+l)*8+j] = W1[kc*32 + (l>>4)*8 + j][hf*16 + (l&15)],  b = kc*8+hf
//   w2p[(b*64+l)*8+j] = W2[ks*32 + (l>>4)*8 + j][tf*16 + (l&15)],  b = ks*4+tf
__global__ void pack_pre(const float* __restrict__ W1, bf16* __restrict__ w1p,
                         const float* __restrict__ W2, bf16* __restrict__ w2p) {
  int b = blockIdx.x, lane = threadIdx.x;
  int mm = lane & 15, qq = lane >> 4;
  if (b < 96) {
    int kc = b >> 3, hf = b & 7;
    bf16x8 r;
    #pragma unroll
    for (int j = 0; j < 8; ++j)
      r[j] = (bf16)W1[(kc * 32 + qq * 8 + j) * 128 + hf * 16 + mm];
    *(bf16x8*)(w1p + ((long)b * 64 + lane) * 8) = r;
  } else {
    int bb = b - 96;
    int ks = bb >> 2, tf = bb & 3;
    bf16x8 r;
    #pragma unroll
    for (int j = 0; j < 8; ++j)
      r[j] = (bf16)W2[(ks * 32 + qq * 8 + j) * 64 + tf * 16 + mm];
    *(bf16x8*)(w2p + ((long)bb * 64 + lane) * 8) = r;
  }
}

// 32 KB LDS (4 waves x 8KB private slices); (256,2) -> no spill risk.
__global__ __launch_bounds__(256, 2) void edge_mlp(
    const float* __restrict__ ek, const float* __restrict__ vrk, const float* __restrict__ vsk,
    const float* __restrict__ u, const int* __restrict__ batch,
    const bf16* __restrict__ w1p, const float* __restrict__ b1,
    const bf16* __restrict__ w2p, const float* __restrict__ b2,
    float* __restrict__ out)
{
  __shared__ __align__(16) char smem[32768];  // 4 waves x 8 KB
  const int tid  = threadIdx.x;
  const int lane = tid & 63;
  const int wv   = tid >> 6;
  const int m    = lane & 15;
  const int q    = lane >> 4;
  char* wsl = smem + wv * 8192;        // wave slice: x dbuf (2x4KB); later h/out

  const int e0 = blockIdx.x * 128 + wv * 32;   // wave's 32 edges
  const int rl = lane >> 3;                    // 0..7: row within 8-row group
  const int cswz = ((lane & 7) ^ rl) * 16;     // source-side XOR swizzle (bytes)

  // u gather row indices for the DMA (batch sorted; L2/L3-resident)
  int ubr[4];
  #pragma unroll
  for (int i = 0; i < 4; ++i) ubr[i] = batch[e0 + i * 8 + rl];

  const char* cek = (const char*)ek  + (long)e0 * 256;
  const char* cvr = (const char*)vrk + (long)e0 * 512;
  const char* cvs = (const char*)vsk + (long)e0 * 512;
  const char* cu_ = (const char*)u;

  // stage k-chunk kc (32 edges x 32 k, f32, 4KB) at byte bufoff of the slice.
  auto stage = [&](int kc, int bufoff) {
    #pragma unroll
    for (int i = 0; i < 4; ++i) {
      int r = i * 8 + rl;
      const char* src;
      if (kc < 2)       src = cek + (long)r * 256 + kc * 128 + cswz;
      else if (kc < 6)  src = cvr + (long)r * 512 + (kc - 2) * 128 + cswz;
      else if (kc < 10) src = cvs + (long)r * 512 + (kc - 6) * 128 + cswz;
      else              src = cu_ + (long)ubr[i] * 256 + (kc - 10) * 128 + cswz;
      ldg2lds16(src, wsl + bufoff + i * 1024);
    }
  };

  const bf16* wp = w1p + lane * 8;
  const int off0 = ((q << 1) ^ (m & 7)) * 16;  // ds_read swizzled chunk offset

  // ---- prologue: stage(0), W(0).  Queue entering iter 0: stage(0)4, W(0)8.
  stage(0, 0);
  bf16x8 wcur[8], wnxt[8];
  #pragma unroll
  for (int hf = 0; hf < 8; ++hf)
    wcur[hf] = *(const bf16x8*)(wp + hf * 512);
  __builtin_amdgcn_sched_barrier(0);

  // ---- GEMM1: acc[hf][ef] = D[hid][edge]; K = 384 in 12 chunks of 32
  floatx4 acc[8][2] = {};
  #pragma unroll
  for (int kc = 0; kc < 12; ++kc) {
    const int curoff = (kc & 1) * 4096;
    // s1: next W fragments (register prefetch, consumed NEXT iteration)
    if (kc < 11) {
      #pragma unroll
      for (int hf = 0; hf < 8; ++hf)
        wnxt[hf] = *(const bf16x8*)(wp + ((kc + 1) * 8 + hf) * 512);
    }
    __builtin_amdgcn_sched_barrier(0);
    // s2: queue next x chunk (prefetch distance 1)
    if (kc < 11) stage(kc + 1, curoff ^ 4096);
    __builtin_amdgcn_sched_barrier(0);
    // s3: counted wait. Retires exactly {W(kc), stage(kc)} (oldest 12);
    // keeps {W(kc+1), stage(kc+1)} in flight. Final iter drains all.
    if (kc < 11) asm volatile("s_waitcnt vmcnt(12)" ::: "memory");
    else         asm volatile("s_waitcnt vmcnt(0)"  ::: "memory");
    __builtin_amdgcn_sched_barrier(0);
    // s4: x fragments: ds_read f32 -> cvt bf16
    bf16x8 xv[2];
    #pragma unroll
    for (int ef = 0; ef < 2; ++ef) {
      const char* p = wsl + curoff + (ef * 16 + m) * 128;
      floatx4 lo = *(const floatx4*)(p + off0);
      floatx4 hi = *(const floatx4*)(p + (off0 ^ 16));
      xv[ef] = cvt_b8(lo, hi);
    }
    // s5: MFMA with wcur (already retired by this iteration's vmcnt)
    #pragma unroll
    for (int hf = 0; hf < 8; ++hf) {
      acc[hf][0] = __builtin_amdgcn_mfma_f32_16x16x32_bf16(wcur[hf], xv[0], acc[hf][0], 0, 0, 0);
      acc[hf][1] = __builtin_amdgcn_mfma_f32_16x16x32_bf16(wcur[hf], xv[1], acc[hf][1], 0, 0, 0);
    }
    // rotate (full unroll -> static indices, pure register renaming)
    if (kc < 11) {
      #pragma unroll
      for (int hf = 0; hf < 8; ++hf) wcur[hf] = wnxt[hf];
    }
  }

  // ---- epilogue 1: bias + relu + bf16 -> wave-private LDS h (XOR-16 swizzle)
  // (aliases the x dbuf; safe: final vmcnt(0) drained all DMA, and all x
  //  ds_reads were consumed by GEMM1's MFMAs; same-wave DS ops are in-order)
  bf16* hsp = (bf16*)wsl;                    // [32 edge][128 hid]
  #pragma unroll
  for (int hf = 0; hf < 8; ++hf) {
    floatx4 b1v = *(const floatx4*)(b1 + hf * 16 + q * 4);
    #pragma unroll
    for (int ef = 0; ef < 2; ++ef) {
      floatx4 v = acc[hf][ef] + b1v;
      v.x = v.x > 0.f ? v.x : 0.f;
      v.y = v.y > 0.f ? v.y : 0.f;
      v.z = v.z > 0.f ? v.z : 0.f;
      v.w = v.w > 0.f ? v.w : 0.f;
      int r_e  = ef * 16 + m;
      int c    = hf * 2 + (q >> 1);          // 16B chunk of hid0 = hf*16+q*4
      int phys = c ^ (r_e & 15);
      *(bf16x4*)(hsp + r_e * 128 + phys * 8 + (q & 1) * 4) = cvt_b4(v);
    }
  }
  asm volatile("s_waitcnt lgkmcnt(0)" ::: "memory");   // h writes visible
  __builtin_amdgcn_sched_barrier(0);

  // ---- GEMM2: acc2[tf][ef] = D[tgt][edge]; K = 128 in 4 steps of 32
  floatx4 acc2[4][2] = {};
  const bf16* wq = w2p + lane * 8;
  bf16x8 w2r[16];
  #pragma unroll
  for (int f = 0; f < 16; ++f) w2r[f] = *(const bf16x8*)(wq + f * 512);
  #pragma unroll
  for (int ks = 0; ks < 4; ++ks) {
    bf16x8 hb[2];
    #pragma unroll
    for (int ef = 0; ef < 2; ++ef) {
      int r_e  = ef * 16 + m;
      int phys = (ks * 4 + q) ^ (r_e & 15);
      hb[ef] = *(const bf16x8*)(hsp + r_e * 128 + phys * 8);
    }
    #pragma unroll
    for (int tf = 0; tf < 4; ++tf) {
      acc2[tf][0] = __builtin_amdgcn_mfma_f32_16x16x32_bf16(w2r[ks * 4 + tf], hb[0], acc2[tf][0], 0, 0, 0);
      acc2[tf][1] = __builtin_amdgcn_mfma_f32_16x16x32_bf16(w2r[ks * 4 + tf], hb[1], acc2[tf][1], 0, 0, 0);
    }
  }

  // ---- epilogue 2: bias, bounce f32 through LDS slice, store full lines
  asm volatile("s_waitcnt lgkmcnt(0)" ::: "memory");   // h reads done before overwrite
  __builtin_amdgcn_sched_barrier(0);
  float* fs = (float*)wsl;                             // [32 edge][64 tgt] f32
  #pragma unroll
  for (int tf = 0; tf < 4; ++tf) {
    floatx4 b2v = *(const floatx4*)(b2 + tf * 16 + q * 4);
    #pragma unroll
    for (int ef = 0; ef < 2; ++ef) {
      floatx4 v = acc2[tf][ef] + b2v;
      int r_e  = ef * 16 + m;
      int c    = tf * 4 + q;                 // 16B chunk of tgt0 = tf*16+q*4
      int phys = c ^ (r_e & 15);
      *(floatx4*)(fs + r_e * 64 + phys * 4) = v;
    }
  }
  asm volatile("s_waitcnt lgkmcnt(0)" ::: "memory");
  __builtin_amdgcn_sched_barrier(0);

  float* outp = out + (long)e0 * 64;        // wave's 8KB contiguous out region
  #pragma unroll
  for (int i = 0; i < 8; ++i) {
    int r_e  = i * 4 + q;
    int phys = m ^ (r_e & 15);
    floatx4 v = *(const floatx4*)(fs + r_e * 64 + phys * 4);
    *(floatx4*)(outp + i * 256 + lane * 4) = v;   // 1KB contiguous per instruction
  }
}

extern "C" void kernel_launch(void* const* d_in, const int* in_sizes, int n_in,
                              void* d_out, int out_size, void* d_ws, size_t ws_size,
                              hipStream_t stream) {
  const float* ek    = (const float*)d_in[0];
  const float* vrk   = (const float*)d_in[1];
  const float* vsk   = (const float*)d_in[2];
  const float* u     = (const float*)d_in[3];
  const int*   batch = (const int*)d_in[4];
  const float* W1    = (const float*)d_in[5];
  const float* b1    = (const float*)d_in[6];
  const float* W2    = (const float*)d_in[7];
  const float* b2    = (const float*)d_in[8];
  float* out = (float*)d_out;

  bf16* w1p = (bf16*)d_ws;               // 96 frags * 64 lanes * 8 = 96 KB
  bf16* w2p = (bf16*)d_ws + 49152;       // 16 frags * 64 lanes * 8 = 16 KB

  pack_pre<<<112, 64, 0, stream>>>(W1, w1p, W2, w2p);
  edge_mlp<<<2500, 256, 0, stream>>>(ek, vrk, vsk, u, batch, w1p, b1, w2p, b2, out);
}